// Round 9
// baseline (201.770 us; speedup 1.0000x reference)
//
#include <hip/hip_runtime.h>
#include <hip/hip_bf16.h>

typedef __bf16 bf16x8 __attribute__((ext_vector_type(8)));
typedef float f32x4 __attribute__((ext_vector_type(4)));
typedef float f32x16 __attribute__((ext_vector_type(16)));
typedef unsigned int uint;
typedef unsigned short u16;

#define DEV static __device__ __forceinline__

DEV u16 f2bf(float x) {
    uint u = __builtin_bit_cast(uint, x);
    u += 0x7FFFu + ((u >> 16) & 1u);
    return (u16)(u >> 16);
}

DEV uint cvtpk(float lo, float hi) {
    uint r;
    asm("v_cvt_pk_bf16_f32 %0, %1, %2" : "=v"(r) : "v"(lo), "v"(hi));
    return r;
}

DEV void plswap(uint& a, uint& b) {
    asm("v_permlane32_swap_b32 %0, %1" : "+v"(a), "+v"(b));
}

DEV float max3f(float a, float b, float c) {
    float d;
    asm("v_max3_f32 %0, %1, %2, %3" : "=v"(d) : "v"(a), "v"(b), "v"(c));
    return d;
}

DEV float fexp2(float x) { return __builtin_amdgcn_exp2f(x); }

DEV void gload16(const void* g, void* l) {
    __builtin_amdgcn_global_load_lds((const __attribute__((address_space(1))) void*)g,
                                     (__attribute__((address_space(3))) void*)l,
                                     16, 0, 0);
}

// 8x8 u16 transpose among lanes (bits 3,4,5 of lane id) -- verified r1-r3
DEV uint4 xpose8(uint4 vd, int l) {
    uint w0 = vd.x, w1 = vd.y, w2 = vd.z, w3 = vd.w;
    {
        int lam = (l >> 5) & 1;
        uint s0 = lam ? w0 : w2, s1 = lam ? w1 : w3;
        uint t0 = __shfl_xor(s0, 32), t1 = __shfl_xor(s1, 32);
        if (lam) { w0 = t0; w1 = t1; } else { w2 = t0; w3 = t1; }
    }
    {
        int lam = (l >> 4) & 1;
        uint s0 = lam ? w0 : w1, s1 = lam ? w2 : w3;
        uint t0 = __shfl_xor(s0, 16), t1 = __shfl_xor(s1, 16);
        if (lam) { w0 = t0; w2 = t1; } else { w1 = t0; w3 = t1; }
    }
    {
        int lam = (l >> 3) & 1;
        uint sA = lam ? ((w0 & 0xFFFFu) | (w1 << 16)) : ((w0 >> 16) | (w1 & 0xFFFF0000u));
        uint sB = lam ? ((w2 & 0xFFFFu) | (w3 << 16)) : ((w2 >> 16) | (w3 & 0xFFFF0000u));
        uint tA = __shfl_xor(sA, 8), tB = __shfl_xor(sB, 8);
        if (lam) {
            w0 = (w0 & 0xFFFF0000u) | (tA & 0xFFFFu);
            w1 = (w1 & 0xFFFF0000u) | (tA >> 16);
            w2 = (w2 & 0xFFFF0000u) | (tB & 0xFFFFu);
            w3 = (w3 & 0xFFFF0000u) | (tB >> 16);
        } else {
            w0 = (w0 & 0xFFFFu) | (tA << 16);
            w1 = (w1 & 0xFFFFu) | (tA & 0xFFFF0000u);
            w2 = (w2 & 0xFFFFu) | (tB << 16);
            w3 = (w3 & 0xFFFFu) | (tB & 0xFFFF0000u);
        }
    }
    return make_uint4(w0, w1, w2, w3);
}

// ---------------- all-4-weights fp32 -> bf16, one launch ---------------------
__global__ __launch_bounds__(256) void k_wconv(const float* __restrict__ w0,
                                               const float* __restrict__ w1,
                                               const float* __restrict__ w2,
                                               const float* __restrict__ w3,
                                               u16* __restrict__ out) {
    const int which = blockIdx.x >> 9;
    const float* in = which == 0 ? w0 : (which == 1 ? w1 : (which == 2 ? w2 : w3));
    const long i = (blockIdx.x & 511) * 256 + threadIdx.x;
    const float4* p = (const float4*)in + i * 2;
    float4 a = p[0], b = p[1];
    uint4 dv;
    dv.x = cvtpk(a.x, a.y); dv.y = cvtpk(a.z, a.w);
    dv.z = cvtpk(b.x, b.y); dv.w = cvtpk(b.z, b.w);
    ((uint4*)(out + ((long)which << 20)))[i] = dv;
}

// ---------------- fused QKV GEMM, double-buffered + software-pipelined -------
// Per iteration: issue B(kt+1) gload_lds + A(kt+1) fp32 loads BEFORE the MFMA
// block; cvt+ds_write A(kt+1) AFTER it; one barrier per K-step. A/B load
// latency hides under compute (T14/T3).
__global__ __launch_bounds__(256, 2) void k_gemm_qkv(
    const float* __restrict__ Aq, const float* __restrict__ Ak,
    const float* __restrict__ Av, const u16* __restrict__ Bw,
    const float* __restrict__ b0, const float* __restrict__ b1,
    const float* __restrict__ b2, u16* __restrict__ Cb) {
    constexpr int N = 1024, K = 1024;
    __shared__ u16 lA[2][8192];
    __shared__ u16 lB[2][8192];
    const int tid = threadIdx.x;
    const int l = tid & 63, w = tid >> 6;
    const int lr = l & 15, lk = l >> 4;
    const int wr = w >> 1, wc = w & 1;
    const int nbn = N >> 7;
    const int cpx = (int)gridDim.x >> 3;
    const int wg = (blockIdx.x & 7) * cpx + (blockIdx.x >> 3);
    const int bm = wg / nbn, bn = wg % nbn;
    const int seg = bm >> 6;
    const float* Aseg = seg == 0 ? Aq : (seg == 1 ? Ak : Av);
    const u16* Bseg = Bw + ((long)seg << 20);
    const float* bias = seg == 0 ? b0 : (seg == 1 ? b1 : b2);
    const int bml = bm & 63;

    const int arow = tid >> 3;
    const int acol = (tid & 7) * 8;
    int adst[4];
    const float* asrc[4];
#pragma unroll
    for (int t = 0; t < 4; ++t) {
        int row = t * 32 + arow;
        adst[t] = row * 128 + ((acol * 2) ^ ((row & 7) << 4));
        asrc[t] = Aseg + (long)(bml * 128 + row) * K + acol;
    }
    long bbase[4];
    int bdst[4];
#pragma unroll
    for (int t = 0; t < 4; ++t) {
        int p = (t * 256 + tid) * 16;
        int row = p >> 7;
        int src = (p & 127) ^ ((row & 7) << 4);
        bdst[t] = p;
        bbase[t] = (long)(bn * 128 + row) * (K * 2) + src;
    }
    const int swz = (lr & 7) << 4;
    int aoff[4][2], boff[4][2];
#pragma unroll
    for (int m = 0; m < 4; ++m)
#pragma unroll
        for (int kc = 0; kc < 2; ++kc) {
            aoff[m][kc] = (wr * 64 + m * 16 + lr) * 128 + ((kc * 64 + lk * 16) ^ swz);
            boff[m][kc] = (wc * 64 + m * 16 + lr) * 128 + ((kc * 64 + lk * 16) ^ swz);
        }

    f32x4 acc[4][4] = {};
    const char* gB = (const char*)Bseg;
    float4 f0[4], f1[4];

#define LOADA(kt_) do {                                                        \
        _Pragma("unroll")                                                      \
        for (int t = 0; t < 4; ++t) {                                          \
            const float* s = asrc[t] + (kt_) * 64;                             \
            f0[t] = *(const float4*)s;                                         \
            f1[t] = *(const float4*)(s + 4);                                   \
        }                                                                      \
    } while (0)
#define WRITEA(buf_) do {                                                      \
        _Pragma("unroll")                                                      \
        for (int t = 0; t < 4; ++t) {                                          \
            uint4 dv;                                                          \
            dv.x = cvtpk(f0[t].x, f0[t].y);                                    \
            dv.y = cvtpk(f0[t].z, f0[t].w);                                    \
            dv.z = cvtpk(f1[t].x, f1[t].y);                                    \
            dv.w = cvtpk(f1[t].z, f1[t].w);                                    \
            *(uint4*)((char*)lA[buf_] + adst[t]) = dv;                         \
        }                                                                      \
    } while (0)
#define LOADB(kt_, buf_) do {                                                  \
        _Pragma("unroll")                                                      \
        for (int t = 0; t < 4; ++t)                                            \
            gload16(gB + bbase[t] + (kt_) * 128, (char*)lB[buf_] + bdst[t]);   \
    } while (0)

    // prologue: stage tile 0
    LOADA(0);
    LOADB(0, 0);
    WRITEA(0);
    __syncthreads();

    for (int kt = 0; kt < K / 64; ++kt) {
        const int cur = kt & 1;
        if (kt + 1 < K / 64) {
            LOADB(kt + 1, cur ^ 1);
            LOADA(kt + 1);
        }
        const char* lAb = (const char*)lA[cur];
        const char* lBb = (const char*)lB[cur];
#pragma unroll
        for (int kc = 0; kc < 2; ++kc) {
            bf16x8 av[4], bv[4];
#pragma unroll
            for (int m = 0; m < 4; ++m) av[m] = *(const bf16x8*)(lAb + aoff[m][kc]);
#pragma unroll
            for (int n = 0; n < 4; ++n) bv[n] = *(const bf16x8*)(lBb + boff[n][kc]);
#pragma unroll
            for (int m = 0; m < 4; ++m)
#pragma unroll
                for (int n = 0; n < 4; ++n)
                    acc[m][n] = __builtin_amdgcn_mfma_f32_16x16x32_bf16(av[m], bv[n], acc[m][n], 0, 0, 0);
        }
        if (kt + 1 < K / 64)
            WRITEA(cur ^ 1);
        __syncthreads();
    }
#undef LOADA
#undef WRITEA
#undef LOADB

    const int col0 = bn * 128 + wc * 64;
    float bval[4];
#pragma unroll
    for (int n = 0; n < 4; ++n) bval[n] = bias[col0 + n * 16 + lr];
    const int row0 = bm * 128 + wr * 64;
#pragma unroll
    for (int m = 0; m < 4; ++m)
#pragma unroll
        for (int j = 0; j < 4; ++j) {
            int row = row0 + m * 16 + lk * 4 + j;
#pragma unroll
            for (int n = 0; n < 4; ++n)
                Cb[(long)row * N + col0 + n * 16 + lr] = f2bf(acc[m][n][j] + bval[n]);
        }
}

// ---------------- standalone V transpose: V[8192][1024] -> VT[bh*64+dh][2048]
__global__ __launch_bounds__(256) void k_vtrans(const u16* __restrict__ V,
                                                u16* __restrict__ VT) {
    __shared__ u16 lds[64 * 40];   // [ch][4 parts x 8 u16], row stride 80 B
    const int tid = threadIdx.x;
    const int l = tid & 63, w = tid >> 6;
    const int vr = l >> 3, vdb = l & 7;
    const int bid = blockIdx.x;
    const int bh = bid & 63, tc = bid >> 6;
    const int b = bh >> 4, h = bh & 15;
    const int t0 = tc * 32;

    const u16* src = V + ((long)(b * 2048 + t0 + w * 8 + vr) * 1024 + h * 64 + vdb * 8);
    uint4 vd = *(const uint4*)src;
    uint4 tt = xpose8(vd, l);
    *(uint4*)((char*)lds + (vdb * 8 + vr) * 80 + w * 16) = tt;
    __syncthreads();
    const int ch2 = tid >> 2, part = tid & 3;
    uint4 r = *(const uint4*)((const char*)lds + ch2 * 80 + part * 16);
    *(uint4*)(VT + ((long)(bh * 64 + ch2) * 2048 + t0 + part * 8)) = r;
}

// ---------------- bf16 GEMM (Wo projection), fp32 out ------------------------
__global__ __launch_bounds__(256, 2) void k_gemm_bt(
    const u16* __restrict__ A, const u16* __restrict__ Bw,
    const float* __restrict__ bias, float* __restrict__ Cf,
    int M, int N, int K) {
    __shared__ u16 lA[128 * 64];
    __shared__ u16 lB[128 * 64];
    const int tid = threadIdx.x;
    const int l = tid & 63, w = tid >> 6;
    const int lr = l & 15, lk = l >> 4;
    const int wr = w >> 1, wc = w & 1;
    const int nbn = N >> 7;
    const int cpx = (int)gridDim.x >> 3;
    const int wg = (blockIdx.x & 7) * cpx + (blockIdx.x >> 3);
    const int bm = wg / nbn, bn = wg % nbn;

    long abase[4], bbase[4];
    int ldst[4];
#pragma unroll
    for (int t = 0; t < 4; ++t) {
        int c = t * 256 + tid;
        int p = c * 16;
        int row = p >> 7;
        int inrow = p & 127;
        int src = inrow ^ ((row & 7) << 4);
        ldst[t] = p;
        abase[t] = (long)(bm * 128 + row) * (K * 2) + src;
        bbase[t] = (long)(bn * 128 + row) * (K * 2) + src;
    }
    const int swz = (lr & 7) << 4;
    int aoff[4][2], boff[4][2];
#pragma unroll
    for (int m = 0; m < 4; ++m)
#pragma unroll
        for (int kc = 0; kc < 2; ++kc) {
            aoff[m][kc] = (wr * 64 + m * 16 + lr) * 128 + ((kc * 64 + lk * 16) ^ swz);
            boff[m][kc] = (wc * 64 + m * 16 + lr) * 128 + ((kc * 64 + lk * 16) ^ swz);
        }

    f32x4 acc[4][4] = {};
    const char* gA = (const char*)A;
    const char* gB = (const char*)Bw;
    const char* lAb = (const char*)lA;
    const char* lBb = (const char*)lB;
    const int nkt = K >> 6;
    for (int kt = 0; kt < nkt; ++kt) {
        __syncthreads();
#pragma unroll
        for (int t = 0; t < 4; ++t)
            gload16(gA + abase[t] + kt * 128, (char*)lA + ldst[t]);
#pragma unroll
        for (int t = 0; t < 4; ++t)
            gload16(gB + bbase[t] + kt * 128, (char*)lB + ldst[t]);
        __syncthreads();
#pragma unroll
        for (int kc = 0; kc < 2; ++kc) {
            bf16x8 av[4], bv[4];
#pragma unroll
            for (int m = 0; m < 4; ++m) av[m] = *(const bf16x8*)(lAb + aoff[m][kc]);
#pragma unroll
            for (int n = 0; n < 4; ++n) bv[n] = *(const bf16x8*)(lBb + boff[n][kc]);
#pragma unroll
            for (int m = 0; m < 4; ++m)
#pragma unroll
                for (int n = 0; n < 4; ++n)
                    acc[m][n] = __builtin_amdgcn_mfma_f32_16x16x32_bf16(av[m], bv[n], acc[m][n], 0, 0, 0);
        }
    }

    const int row0 = bm * 128 + wr * 64;
    const int col0 = bn * 128 + wc * 64;
    float bval[4];
#pragma unroll
    for (int n = 0; n < 4; ++n) bval[n] = bias[col0 + n * 16 + lr];
#pragma unroll
    for (int m = 0; m < 4; ++m)
#pragma unroll
        for (int j = 0; j < 4; ++j) {
            int row = row0 + m * 16 + lk * 4 + j;
#pragma unroll
            for (int n = 0; n < 4; ++n)
                Cf[(long)row * N + col0 + n * 16 + lr] = acc[m][n][j] + bval[n];
        }
}

// ---------------- flash attention v5: V^T pre-transposed in global -----------
__global__ __launch_bounds__(512, 4) void k_attn5(
    const u16* __restrict__ Qb, const u16* __restrict__ Kb,
    const u16* __restrict__ VTb, u16* __restrict__ Ob) {
    constexpr int T = 2048, D = 1024;
    constexpr int NT = T / 64;
    __shared__ u16 sK[2][4096];
    __shared__ u16 sV[2][4096];
    const int tid = threadIdx.x;
    const int l = tid & 63, w = tid >> 6;
    const int hi = l >> 5;
    const int q32 = l & 31;
    const int hi16 = hi * 16;
    const int kswz = (q32 & 7) << 4;
    const int bid = blockIdx.x;
    const int bh = (bid & 7) * 8 + ((bid >> 3) & 7);
    const int qt = bid >> 6;
    const int b = bh >> 4, h = bh & 15;

    const char* Qg = (const char*)(Qb + (long)b * T * D + h * 64);
    const char* Kg = (const char*)(Kb + (long)b * T * D + h * 64);
    const char* VTg = (const char*)(VTb + (long)bh * 64 * 2048);
    const int q0 = qt * 256 + w * 32;

    bf16x8 qf[4];
#pragma unroll
    for (int c = 0; c < 4; ++c)
        qf[c] = *(const bf16x8*)(Qg + (long)(q0 + q32) * 2048 + c * 32 + hi16);

    const int srow = tid >> 3;
    const int ssrc = ((tid & 7) * 16) ^ ((srow & 7) << 4);
    const int sdst = tid * 16;
    const long kbase = (long)srow * 2048 + ssrc;
    const long vbase = (long)srow * 4096 + ssrc;

    union { u16 s[8]; bf16x8 v; } ones_u;
#pragma unroll
    for (int i = 0; i < 8; ++i) ones_u.s[i] = 0x3F80;
    const bf16x8 onesv = ones_u.v;

#define STAGE(kt_, buf_) do {                                                  \
        gload16(Kg + (long)(kt_) * 64 * 2048 + kbase, (char*)sK[buf_] + sdst); \
        gload16(VTg + (kt_) * 128 + vbase, (char*)sV[buf_] + sdst);            \
    } while (0)

    STAGE(0, 0);
    __syncthreads();

    f32x16 o[2] = {};
    f32x16 lacc = {};
    float m = -1e30f;
    const float k1 = 0.18033688f;
    const float THR = 44.3616f;

    for (int kt = 0; kt < NT; ++kt) {
        if (kt + 1 < NT) STAGE(kt + 1, (kt + 1) & 1);

        const char* kbp = (const char*)sK[kt & 1];
        f32x16 st[2] = {};
        __builtin_amdgcn_s_setprio(1);
#pragma unroll
        for (int c = 0; c < 4; ++c) {
            bf16x8 kf = *(const bf16x8*)(kbp + q32 * 128 + ((c * 32 + hi16) ^ kswz));
            st[0] = __builtin_amdgcn_mfma_f32_32x32x16_bf16(kf, qf[c], st[0], 0, 0, 0);
        }
#pragma unroll
        for (int c = 0; c < 4; ++c) {
            bf16x8 kf = *(const bf16x8*)(kbp + (32 + q32) * 128 + ((c * 32 + hi16) ^ kswz));
            st[1] = __builtin_amdgcn_mfma_f32_32x32x16_bf16(kf, qf[c], st[1], 0, 0, 0);
        }
        __builtin_amdgcn_s_setprio(0);

        float t0 = max3f(st[0][0], st[0][1], st[0][2]);
        float t1 = max3f(st[0][3], st[0][4], st[0][5]);
        float t2 = max3f(st[0][6], st[0][7], st[0][8]);
        float t3 = max3f(st[0][9], st[0][10], st[0][11]);
        float t4 = max3f(st[0][12], st[0][13], st[0][14]);
        float t5 = max3f(st[1][0], st[1][1], st[1][2]);
        float t6 = max3f(st[1][3], st[1][4], st[1][5]);
        float t7 = max3f(st[1][6], st[1][7], st[1][8]);
        float t8 = max3f(st[1][9], st[1][10], st[1][11]);
        float t9 = max3f(st[1][12], st[1][13], st[1][14]);
        float u0 = max3f(t0, t1, t2);
        float u1 = max3f(t3, t4, st[0][15]);
        float u2 = max3f(t5, t6, t7);
        float u3 = max3f(t8, t9, st[1][15]);
        float rm = fmaxf(max3f(u0, u1, u2), u3);

        bool defer = __all(rm <= m + THR);
        if (!defer) {
            float rmw = fmaxf(rm, __shfl_xor(rm, 32));
            float mn = fmaxf(m, rmw);
            float aq = fexp2((m - mn) * k1);
            m = mn;
#pragma unroll
            for (int r = 0; r < 16; ++r) {
                int src = (r & 3) + 8 * (r >> 2) + 4 * hi;
                float ar = __shfl(aq, src);
                o[0][r] *= ar;
                o[1][r] *= ar;
                lacc[r] *= ar;
            }
        }
        float mk = m * k1;
#pragma unroll
        for (int n = 0; n < 2; ++n)
#pragma unroll
            for (int r = 0; r < 16; ++r)
                st[n][r] = fexp2(fmaf(st[n][r], k1, -mk));

        const char* vbp = (const char*)sV[kt & 1];
        __builtin_amdgcn_s_setprio(1);
#pragma unroll
        for (int c = 0; c < 4; ++c) {
            const int n = c >> 1, rb = (c & 1) * 8;
            uint A0 = cvtpk(st[n][rb + 0], st[n][rb + 1]);
            uint A1 = cvtpk(st[n][rb + 2], st[n][rb + 3]);
            uint B0 = cvtpk(st[n][rb + 4], st[n][rb + 5]);
            uint B1 = cvtpk(st[n][rb + 6], st[n][rb + 7]);
            plswap(A0, B0);
            plswap(A1, B1);
            union { uint u[4]; bf16x8 v; } pa;
            pa.u[0] = A0; pa.u[1] = A1; pa.u[2] = B0; pa.u[3] = B1;
            int cb = c * 32 + hi16;
            bf16x8 v0 = *(const bf16x8*)(vbp + q32 * 128 + (cb ^ kswz));
            bf16x8 v1 = *(const bf16x8*)(vbp + (32 + q32) * 128 + (cb ^ kswz));
            o[0] = __builtin_amdgcn_mfma_f32_32x32x16_bf16(pa.v, v0, o[0], 0, 0, 0);
            o[1] = __builtin_amdgcn_mfma_f32_32x32x16_bf16(pa.v, v1, o[1], 0, 0, 0);
            lacc  = __builtin_amdgcn_mfma_f32_32x32x16_bf16(pa.v, onesv, lacc, 0, 0, 0);
        }
        __builtin_amdgcn_s_setprio(0);
        __syncthreads();
    }
#undef STAGE

#pragma unroll
    for (int r = 0; r < 16; ++r) {
        float inv = 1.f / lacc[r];
        int srcq = (r & 3) + 8 * (r >> 2) + 4 * hi;
        int trow = q0 + srcq;
        char* orow = (char*)Ob + ((long)(b * T + trow) * D + h * 64) * 2;
        *(u16*)(orow + q32 * 2) = f2bf(o[0][r] * inv);
        *(u16*)(orow + (32 + q32) * 2) = f2bf(o[1][r] * inv);
    }
}

// ---------------------------------------------------------------------------
extern "C" void kernel_launch(void* const* d_in, const int* in_sizes, int n_in,
                              void* d_out, int out_size, void* d_ws, size_t ws_size,
                              hipStream_t stream) {
    const float* q  = (const float*)d_in[0];
    const float* k  = (const float*)d_in[1];
    const float* v  = (const float*)d_in[2];
    const float* Wq = (const float*)d_in[3];
    const float* bq = (const float*)d_in[4];
    const float* Wk = (const float*)d_in[5];
    const float* bk = (const float*)d_in[6];
    const float* Wv = (const float*)d_in[7];
    const float* bv = (const float*)d_in[8];
    const float* Wo = (const float*)d_in[9];
    const float* bo = (const float*)d_in[10];

    const long MT = 8192L * 1024;
    const long WT = 1024L * 1024;
    u16* ws   = (u16*)d_ws;
    u16* wall = ws;                    // Wq|Wk|Wv|Wo bf16, stacked
    u16* qbf  = wall + 4 * WT;         // Q|K|V row-major outputs (3*MT)
    u16* kbf  = qbf + MT;
    u16* vbf  = kbf + MT;
    u16* vtb  = vbf + MT;              // V^T [bh][dh][t]
    u16* abf  = vtb + MT;              // attention output

    k_wconv<<<dim3(2048), dim3(256), 0, stream>>>(Wq, Wk, Wv, Wo, wall);

    k_gemm_qkv<<<dim3(1536), dim3(256), 0, stream>>>(q, k, v, wall,
                                                     bq, bk, bv, qbf);

    k_vtrans<<<dim3(4096), dim3(256), 0, stream>>>(vbf, vtb);

    k_attn5<<<dim3(512), dim3(512), 0, stream>>>(qbf, kbf, vtb, abf);

    k_gemm_bt<<<dim3(512), dim3(256), 0, stream>>>(abf, wall + 3 * WT, bo,
                                                   (float*)d_out, 8192, 1024, 1024);
}

// Round 10
// 190.950 us; speedup vs baseline: 1.0567x; 1.0567x over previous
//
#include <hip/hip_runtime.h>
#include <hip/hip_bf16.h>

typedef __bf16 bf16x8 __attribute__((ext_vector_type(8)));
typedef float f32x4 __attribute__((ext_vector_type(4)));
typedef float f32x16 __attribute__((ext_vector_type(16)));
typedef unsigned int uint;
typedef unsigned short u16;

#define DEV static __device__ __forceinline__

DEV u16 f2bf(float x) {
    uint u = __builtin_bit_cast(uint, x);
    u += 0x7FFFu + ((u >> 16) & 1u);
    return (u16)(u >> 16);
}

DEV uint cvtpk(float lo, float hi) {
    uint r;
    asm("v_cvt_pk_bf16_f32 %0, %1, %2" : "=v"(r) : "v"(lo), "v"(hi));
    return r;
}

DEV void plswap(uint& a, uint& b) {
    asm("v_permlane32_swap_b32 %0, %1" : "+v"(a), "+v"(b));
}

DEV float max3f(float a, float b, float c) {
    float d;
    asm("v_max3_f32 %0, %1, %2, %3" : "=v"(d) : "v"(a), "v"(b), "v"(c));
    return d;
}

DEV float fexp2(float x) { return __builtin_amdgcn_exp2f(x); }

DEV void gload16(const void* g, void* l) {
    __builtin_amdgcn_global_load_lds((const __attribute__((address_space(1))) void*)g,
                                     (__attribute__((address_space(3))) void*)l,
                                     16, 0, 0);
}

// 8x8 u16 transpose among lanes (bits 3,4,5 of lane id) -- verified r1-r3
DEV uint4 xpose8(uint4 vd, int l) {
    uint w0 = vd.x, w1 = vd.y, w2 = vd.z, w3 = vd.w;
    {
        int lam = (l >> 5) & 1;
        uint s0 = lam ? w0 : w2, s1 = lam ? w1 : w3;
        uint t0 = __shfl_xor(s0, 32), t1 = __shfl_xor(s1, 32);
        if (lam) { w0 = t0; w1 = t1; } else { w2 = t0; w3 = t1; }
    }
    {
        int lam = (l >> 4) & 1;
        uint s0 = lam ? w0 : w1, s1 = lam ? w2 : w3;
        uint t0 = __shfl_xor(s0, 16), t1 = __shfl_xor(s1, 16);
        if (lam) { w0 = t0; w2 = t1; } else { w1 = t0; w3 = t1; }
    }
    {
        int lam = (l >> 3) & 1;
        uint sA = lam ? ((w0 & 0xFFFFu) | (w1 << 16)) : ((w0 >> 16) | (w1 & 0xFFFF0000u));
        uint sB = lam ? ((w2 & 0xFFFFu) | (w3 << 16)) : ((w2 >> 16) | (w3 & 0xFFFF0000u));
        uint tA = __shfl_xor(sA, 8), tB = __shfl_xor(sB, 8);
        if (lam) {
            w0 = (w0 & 0xFFFF0000u) | (tA & 0xFFFFu);
            w1 = (w1 & 0xFFFF0000u) | (tA >> 16);
            w2 = (w2 & 0xFFFF0000u) | (tB & 0xFFFFu);
            w3 = (w3 & 0xFFFF0000u) | (tB >> 16);
        } else {
            w0 = (w0 & 0xFFFFu) | (tA << 16);
            w1 = (w1 & 0xFFFFu) | (tA & 0xFFFF0000u);
            w2 = (w2 & 0xFFFFu) | (tB << 16);
            w3 = (w3 & 0xFFFFu) | (tB & 0xFFFF0000u);
        }
    }
    return make_uint4(w0, w1, w2, w3);
}

// ---------------- all-4-weights fp32 -> bf16, one launch ---------------------
__global__ __launch_bounds__(256) void k_wconv(const float* __restrict__ w0,
                                               const float* __restrict__ w1,
                                               const float* __restrict__ w2,
                                               const float* __restrict__ w3,
                                               u16* __restrict__ out) {
    const int which = blockIdx.x >> 9;
    const float* in = which == 0 ? w0 : (which == 1 ? w1 : (which == 2 ? w2 : w3));
    const long i = (blockIdx.x & 511) * 256 + threadIdx.x;
    const float4* p = (const float4*)in + i * 2;
    float4 a = p[0], b = p[1];
    uint4 dv;
    dv.x = cvtpk(a.x, a.y); dv.y = cvtpk(a.z, a.w);
    dv.z = cvtpk(b.x, b.y); dv.w = cvtpk(b.z, b.w);
    ((uint4*)(out + ((long)which << 20)))[i] = dv;
}

// ---------------- fused QKV GEMM (fp32 A -> bf16 in-kernel), 4 blk/CU --------
__global__ __launch_bounds__(256, 4) void k_gemm_qkv(
    const float* __restrict__ Aq, const float* __restrict__ Ak,
    const float* __restrict__ Av, const u16* __restrict__ Bw,
    const float* __restrict__ b0, const float* __restrict__ b1,
    const float* __restrict__ b2, u16* __restrict__ Cb) {
    constexpr int N = 1024, K = 1024;
    __shared__ u16 lA[128 * 64];
    __shared__ u16 lB[128 * 64];
    const int tid = threadIdx.x;
    const int l = tid & 63, w = tid >> 6;
    const int lr = l & 15, lk = l >> 4;
    const int wr = w >> 1, wc = w & 1;
    const int nbn = N >> 7;
    const int cpx = (int)gridDim.x >> 3;
    const int wg = (blockIdx.x & 7) * cpx + (blockIdx.x >> 3);
    const int bm = wg / nbn, bn = wg % nbn;
    const int seg = bm >> 6;
    const float* Aseg = seg == 0 ? Aq : (seg == 1 ? Ak : Av);
    const u16* Bseg = Bw + ((long)seg << 20);
    const float* bias = seg == 0 ? b0 : (seg == 1 ? b1 : b2);
    const int bml = bm & 63;

    const int arow = tid >> 3;
    const int acol = (tid & 7) * 8;
    int adst[4];
    const float* asrc[4];
#pragma unroll
    for (int t = 0; t < 4; ++t) {
        int row = t * 32 + arow;
        adst[t] = row * 128 + ((acol * 2) ^ ((row & 7) << 4));
        asrc[t] = Aseg + (long)(bml * 128 + row) * K + acol;
    }
    long bbase[4];
    int bdst[4];
#pragma unroll
    for (int t = 0; t < 4; ++t) {
        int p = (t * 256 + tid) * 16;
        int row = p >> 7;
        int src = (p & 127) ^ ((row & 7) << 4);
        bdst[t] = p;
        bbase[t] = (long)(bn * 128 + row) * (K * 2) + src;
    }
    const int swz = (lr & 7) << 4;
    int aoff[4][2], boff[4][2];
#pragma unroll
    for (int m = 0; m < 4; ++m)
#pragma unroll
        for (int kc = 0; kc < 2; ++kc) {
            aoff[m][kc] = (wr * 64 + m * 16 + lr) * 128 + ((kc * 64 + lk * 16) ^ swz);
            boff[m][kc] = (wc * 64 + m * 16 + lr) * 128 + ((kc * 64 + lk * 16) ^ swz);
        }

    f32x4 acc[4][4] = {};
    const char* gB = (const char*)Bseg;
    const char* lAb = (const char*)lA;
    const char* lBb = (const char*)lB;
    for (int kt = 0; kt < K / 64; ++kt) {
        __syncthreads();
#pragma unroll
        for (int t = 0; t < 4; ++t)
            gload16(gB + bbase[t] + kt * 128, (char*)lB + bdst[t]);
        float4 f0[4], f1[4];
#pragma unroll
        for (int t = 0; t < 4; ++t) {
            const float* s = asrc[t] + kt * 64;
            f0[t] = *(const float4*)s;
            f1[t] = *(const float4*)(s + 4);
        }
#pragma unroll
        for (int t = 0; t < 4; ++t) {
            uint4 dv;
            dv.x = cvtpk(f0[t].x, f0[t].y);
            dv.y = cvtpk(f0[t].z, f0[t].w);
            dv.z = cvtpk(f1[t].x, f1[t].y);
            dv.w = cvtpk(f1[t].z, f1[t].w);
            *(uint4*)((char*)lA + adst[t]) = dv;
        }
        __syncthreads();
#pragma unroll
        for (int kc = 0; kc < 2; ++kc) {
            bf16x8 av[4], bv[4];
#pragma unroll
            for (int m = 0; m < 4; ++m) av[m] = *(const bf16x8*)(lAb + aoff[m][kc]);
#pragma unroll
            for (int n = 0; n < 4; ++n) bv[n] = *(const bf16x8*)(lBb + boff[n][kc]);
#pragma unroll
            for (int m = 0; m < 4; ++m)
#pragma unroll
                for (int n = 0; n < 4; ++n)
                    acc[m][n] = __builtin_amdgcn_mfma_f32_16x16x32_bf16(av[m], bv[n], acc[m][n], 0, 0, 0);
        }
    }

    const int col0 = bn * 128 + wc * 64;
    float bval[4];
#pragma unroll
    for (int n = 0; n < 4; ++n) bval[n] = bias[col0 + n * 16 + lr];
    const int row0 = bm * 128 + wr * 64;
#pragma unroll
    for (int m = 0; m < 4; ++m)
#pragma unroll
        for (int j = 0; j < 4; ++j) {
            int row = row0 + m * 16 + lk * 4 + j;
#pragma unroll
            for (int n = 0; n < 4; ++n)
                Cb[(long)row * N + col0 + n * 16 + lr] = f2bf(acc[m][n][j] + bval[n]);
        }
}

// ---------------- standalone V transpose: V[8192][1024] -> VT[bh*64+dh][2048]
__global__ __launch_bounds__(256) void k_vtrans(const u16* __restrict__ V,
                                                u16* __restrict__ VT) {
    __shared__ u16 lds[64 * 40];   // [ch][4 parts x 8 u16], row stride 80 B
    const int tid = threadIdx.x;
    const int l = tid & 63, w = tid >> 6;
    const int vr = l >> 3, vdb = l & 7;
    const int bid = blockIdx.x;
    const int bh = bid & 63, tc = bid >> 6;
    const int b = bh >> 4, h = bh & 15;
    const int t0 = tc * 32;

    const u16* src = V + ((long)(b * 2048 + t0 + w * 8 + vr) * 1024 + h * 64 + vdb * 8);
    uint4 vd = *(const uint4*)src;
    uint4 tt = xpose8(vd, l);
    *(uint4*)((char*)lds + (vdb * 8 + vr) * 80 + w * 16) = tt;
    __syncthreads();
    const int ch2 = tid >> 2, part = tid & 3;
    uint4 r = *(const uint4*)((const char*)lds + ch2 * 80 + part * 16);
    *(uint4*)(VT + ((long)(bh * 64 + ch2) * 2048 + t0 + part * 8)) = r;
}

// ---------------- bf16 GEMM (Wo projection), fp32 out, 4 blk/CU --------------
__global__ __launch_bounds__(256, 4) void k_gemm_bt(
    const u16* __restrict__ A, const u16* __restrict__ Bw,
    const float* __restrict__ bias, float* __restrict__ Cf,
    int M, int N, int K) {
    __shared__ u16 lA[128 * 64];
    __shared__ u16 lB[128 * 64];
    const int tid = threadIdx.x;
    const int l = tid & 63, w = tid >> 6;
    const int lr = l & 15, lk = l >> 4;
    const int wr = w >> 1, wc = w & 1;
    const int nbn = N >> 7;
    const int cpx = (int)gridDim.x >> 3;
    const int wg = (blockIdx.x & 7) * cpx + (blockIdx.x >> 3);
    const int bm = wg / nbn, bn = wg % nbn;

    long abase[4], bbase[4];
    int ldst[4];
#pragma unroll
    for (int t = 0; t < 4; ++t) {
        int c = t * 256 + tid;
        int p = c * 16;
        int row = p >> 7;
        int inrow = p & 127;
        int src = inrow ^ ((row & 7) << 4);
        ldst[t] = p;
        abase[t] = (long)(bm * 128 + row) * (K * 2) + src;
        bbase[t] = (long)(bn * 128 + row) * (K * 2) + src;
    }
    const int swz = (lr & 7) << 4;
    int aoff[4][2], boff[4][2];
#pragma unroll
    for (int m = 0; m < 4; ++m)
#pragma unroll
        for (int kc = 0; kc < 2; ++kc) {
            aoff[m][kc] = (wr * 64 + m * 16 + lr) * 128 + ((kc * 64 + lk * 16) ^ swz);
            boff[m][kc] = (wc * 64 + m * 16 + lr) * 128 + ((kc * 64 + lk * 16) ^ swz);
        }

    f32x4 acc[4][4] = {};
    const char* gA = (const char*)A;
    const char* gB = (const char*)Bw;
    const char* lAb = (const char*)lA;
    const char* lBb = (const char*)lB;
    const int nkt = K >> 6;
    for (int kt = 0; kt < nkt; ++kt) {
        __syncthreads();
#pragma unroll
        for (int t = 0; t < 4; ++t)
            gload16(gA + abase[t] + kt * 128, (char*)lA + ldst[t]);
#pragma unroll
        for (int t = 0; t < 4; ++t)
            gload16(gB + bbase[t] + kt * 128, (char*)lB + ldst[t]);
        __syncthreads();
#pragma unroll
        for (int kc = 0; kc < 2; ++kc) {
            bf16x8 av[4], bv[4];
#pragma unroll
            for (int m = 0; m < 4; ++m) av[m] = *(const bf16x8*)(lAb + aoff[m][kc]);
#pragma unroll
            for (int n = 0; n < 4; ++n) bv[n] = *(const bf16x8*)(lBb + boff[n][kc]);
#pragma unroll
            for (int m = 0; m < 4; ++m)
#pragma unroll
                for (int n = 0; n < 4; ++n)
                    acc[m][n] = __builtin_amdgcn_mfma_f32_16x16x32_bf16(av[m], bv[n], acc[m][n], 0, 0, 0);
        }
    }

    const int row0 = bm * 128 + wr * 64;
    const int col0 = bn * 128 + wc * 64;
    float bval[4];
#pragma unroll
    for (int n = 0; n < 4; ++n) bval[n] = bias[col0 + n * 16 + lr];
#pragma unroll
    for (int m = 0; m < 4; ++m)
#pragma unroll
        for (int j = 0; j < 4; ++j) {
            int row = row0 + m * 16 + lk * 4 + j;
#pragma unroll
            for (int n = 0; n < 4; ++n)
                Cf[(long)row * N + col0 + n * 16 + lr] = acc[m][n][j] + bval[n];
        }
}

// ---------------- flash attention v5: V^T pre-transposed in global -----------
__global__ __launch_bounds__(512, 4) void k_attn5(
    const u16* __restrict__ Qb, const u16* __restrict__ Kb,
    const u16* __restrict__ VTb, u16* __restrict__ Ob) {
    constexpr int T = 2048, D = 1024;
    constexpr int NT = T / 64;
    __shared__ u16 sK[2][4096];
    __shared__ u16 sV[2][4096];
    const int tid = threadIdx.x;
    const int l = tid & 63, w = tid >> 6;
    const int hi = l >> 5;
    const int q32 = l & 31;
    const int hi16 = hi * 16;
    const int kswz = (q32 & 7) << 4;
    const int bid = blockIdx.x;
    const int bh = (bid & 7) * 8 + ((bid >> 3) & 7);
    const int qt = bid >> 6;
    const int b = bh >> 4, h = bh & 15;

    const char* Qg = (const char*)(Qb + (long)b * T * D + h * 64);
    const char* Kg = (const char*)(Kb + (long)b * T * D + h * 64);
    const char* VTg = (const char*)(VTb + (long)bh * 64 * 2048);
    const int q0 = qt * 256 + w * 32;

    bf16x8 qf[4];
#pragma unroll
    for (int c = 0; c < 4; ++c)
        qf[c] = *(const bf16x8*)(Qg + (long)(q0 + q32) * 2048 + c * 32 + hi16);

    const int srow = tid >> 3;
    const int ssrc = ((tid & 7) * 16) ^ ((srow & 7) << 4);
    const int sdst = tid * 16;
    const long kbase = (long)srow * 2048 + ssrc;
    const long vbase = (long)srow * 4096 + ssrc;

    union { u16 s[8]; bf16x8 v; } ones_u;
#pragma unroll
    for (int i = 0; i < 8; ++i) ones_u.s[i] = 0x3F80;
    const bf16x8 onesv = ones_u.v;

#define STAGE(kt_, buf_) do {                                                  \
        gload16(Kg + (long)(kt_) * 64 * 2048 + kbase, (char*)sK[buf_] + sdst); \
        gload16(VTg + (kt_) * 128 + vbase, (char*)sV[buf_] + sdst);            \
    } while (0)

    STAGE(0, 0);
    __syncthreads();

    f32x16 o[2] = {};
    f32x16 lacc = {};
    float m = -1e30f;
    const float k1 = 0.18033688f;
    const float THR = 44.3616f;

    for (int kt = 0; kt < NT; ++kt) {
        if (kt + 1 < NT) STAGE(kt + 1, (kt + 1) & 1);

        const char* kbp = (const char*)sK[kt & 1];
        f32x16 st[2] = {};
        __builtin_amdgcn_s_setprio(1);
#pragma unroll
        for (int c = 0; c < 4; ++c) {
            bf16x8 kf = *(const bf16x8*)(kbp + q32 * 128 + ((c * 32 + hi16) ^ kswz));
            st[0] = __builtin_amdgcn_mfma_f32_32x32x16_bf16(kf, qf[c], st[0], 0, 0, 0);
        }
#pragma unroll
        for (int c = 0; c < 4; ++c) {
            bf16x8 kf = *(const bf16x8*)(kbp + (32 + q32) * 128 + ((c * 32 + hi16) ^ kswz));
            st[1] = __builtin_amdgcn_mfma_f32_32x32x16_bf16(kf, qf[c], st[1], 0, 0, 0);
        }
        __builtin_amdgcn_s_setprio(0);

        float t0 = max3f(st[0][0], st[0][1], st[0][2]);
        float t1 = max3f(st[0][3], st[0][4], st[0][5]);
        float t2 = max3f(st[0][6], st[0][7], st[0][8]);
        float t3 = max3f(st[0][9], st[0][10], st[0][11]);
        float t4 = max3f(st[0][12], st[0][13], st[0][14]);
        float t5 = max3f(st[1][0], st[1][1], st[1][2]);
        float t6 = max3f(st[1][3], st[1][4], st[1][5]);
        float t7 = max3f(st[1][6], st[1][7], st[1][8]);
        float t8 = max3f(st[1][9], st[1][10], st[1][11]);
        float t9 = max3f(st[1][12], st[1][13], st[1][14]);
        float u0 = max3f(t0, t1, t2);
        float u1 = max3f(t3, t4, st[0][15]);
        float u2 = max3f(t5, t6, t7);
        float u3 = max3f(t8, t9, st[1][15]);
        float rm = fmaxf(max3f(u0, u1, u2), u3);

        bool defer = __all(rm <= m + THR);
        if (!defer) {
            float rmw = fmaxf(rm, __shfl_xor(rm, 32));
            float mn = fmaxf(m, rmw);
            float aq = fexp2((m - mn) * k1);
            m = mn;
#pragma unroll
            for (int r = 0; r < 16; ++r) {
                int src = (r & 3) + 8 * (r >> 2) + 4 * hi;
                float ar = __shfl(aq, src);
                o[0][r] *= ar;
                o[1][r] *= ar;
                lacc[r] *= ar;
            }
        }
        float mk = m * k1;
#pragma unroll
        for (int n = 0; n < 2; ++n)
#pragma unroll
            for (int r = 0; r < 16; ++r)
                st[n][r] = fexp2(fmaf(st[n][r], k1, -mk));

        const char* vbp = (const char*)sV[kt & 1];
        __builtin_amdgcn_s_setprio(1);
#pragma unroll
        for (int c = 0; c < 4; ++c) {
            const int n = c >> 1, rb = (c & 1) * 8;
            uint A0 = cvtpk(st[n][rb + 0], st[n][rb + 1]);
            uint A1 = cvtpk(st[n][rb + 2], st[n][rb + 3]);
            uint B0 = cvtpk(st[n][rb + 4], st[n][rb + 5]);
            uint B1 = cvtpk(st[n][rb + 6], st[n][rb + 7]);
            plswap(A0, B0);
            plswap(A1, B1);
            union { uint u[4]; bf16x8 v; } pa;
            pa.u[0] = A0; pa.u[1] = A1; pa.u[2] = B0; pa.u[3] = B1;
            int cb = c * 32 + hi16;
            bf16x8 v0 = *(const bf16x8*)(vbp + q32 * 128 + (cb ^ kswz));
            bf16x8 v1 = *(const bf16x8*)(vbp + (32 + q32) * 128 + (cb ^ kswz));
            o[0] = __builtin_amdgcn_mfma_f32_32x32x16_bf16(pa.v, v0, o[0], 0, 0, 0);
            o[1] = __builtin_amdgcn_mfma_f32_32x32x16_bf16(pa.v, v1, o[1], 0, 0, 0);
            lacc  = __builtin_amdgcn_mfma_f32_32x32x16_bf16(pa.v, onesv, lacc, 0, 0, 0);
        }
        __builtin_amdgcn_s_setprio(0);
        __syncthreads();
    }
#undef STAGE

#pragma unroll
    for (int r = 0; r < 16; ++r) {
        float inv = 1.f / lacc[r];
        int srcq = (r & 3) + 8 * (r >> 2) + 4 * hi;
        int trow = q0 + srcq;
        char* orow = (char*)Ob + ((long)(b * T + trow) * D + h * 64) * 2;
        *(u16*)(orow + q32 * 2) = f2bf(o[0][r] * inv);
        *(u16*)(orow + (32 + q32) * 2) = f2bf(o[1][r] * inv);
    }
}

// ---------------------------------------------------------------------------
extern "C" void kernel_launch(void* const* d_in, const int* in_sizes, int n_in,
                              void* d_out, int out_size, void* d_ws, size_t ws_size,
                              hipStream_t stream) {
    const float* q  = (const float*)d_in[0];
    const float* k  = (const float*)d_in[1];
    const float* v  = (const float*)d_in[2];
    const float* Wq = (const float*)d_in[3];
    const float* bq = (const float*)d_in[4];
    const float* Wk = (const float*)d_in[5];
    const float* bk = (const float*)d_in[6];
    const float* Wv = (const float*)d_in[7];
    const float* bv = (const float*)d_in[8];
    const float* Wo = (const float*)d_in[9];
    const float* bo = (const float*)d_in[10];

    const long MT = 8192L * 1024;
    const long WT = 1024L * 1024;
    u16* ws   = (u16*)d_ws;
    u16* wall = ws;                    // Wq|Wk|Wv|Wo bf16, stacked
    u16* qbf  = wall + 4 * WT;         // Q|K|V row-major outputs (3*MT)
    u16* kbf  = qbf + MT;
    u16* vbf  = kbf + MT;
    u16* vtb  = vbf + MT;              // V^T [bh][dh][t]
    u16* abf  = vtb + MT;              // attention output

    k_wconv<<<dim3(2048), dim3(256), 0, stream>>>(Wq, Wk, Wv, Wo, wall);

    k_gemm_qkv<<<dim3(1536), dim3(256), 0, stream>>>(q, k, v, wall,
                                                     bq, bk, bv, qbf);

    k_vtrans<<<dim3(4096), dim3(256), 0, stream>>>(vbf, vtb);

    k_attn5<<<dim3(512), dim3(512), 0, stream>>>(qbf, kbf, vtb, abf);

    k_gemm_bt<<<dim3(512), dim3(256), 0, stream>>>(abf, wall + 3 * WT, bo,
                                                   (float*)d_out, 8192, 1024, 1024);
}